// Round 2
// 260.119 us; speedup vs baseline: 1.0468x; 1.0468x over previous
//
#include <hip/hip_runtime.h>
#include <hip/hip_bf16.h>
#include <hip/hip_fp16.h>

typedef _Float16 f16;
typedef __attribute__((ext_vector_type(8))) _Float16 f16x8;
typedef __attribute__((ext_vector_type(4))) float f32x4;

#define N_NODES 100000
#define N_EDGES 800000
#define META 20000
#define AUTHORS 50000
#define BATCH 8192
#define DIM 128
#define CAP 40   // Poisson(~8) edges per (graph,author); P(>40) ~ 1e-16

__device__ __forceinline__ f16x8 cvtf8(const float* p) {
    float4 x = *(const float4*)p, y = *(const float4*)(p + 4);
    f16x8 a;
    a[0] = (f16)x.x; a[1] = (f16)x.y; a[2] = (f16)x.z; a[3] = (f16)x.w;
    a[4] = (f16)y.x; a[5] = (f16)y.y; a[6] = (f16)y.z; a[7] = (f16)y.w;
    return a;
}

// ---------------- K1: all weight prep + batch flag/dense-id in one kernel -----
// blk 0-4 : G_f = Wc[:,co:co+128] @ Wsrc  (MFMA, LDS-transposed B)  -> f16
// blk 5   : biasF, uc (u0,c0,u1,c1)
// blk 6-10: W1F = f16(W1)
// blk 11  : W3F ; blk 12 : W4F
// blk 13-44: first-touch dense-id assignment over data[] (atomicCAS claim)
__global__ __launch_bounds__(256) void k_prep_fuse(
    const float* __restrict__ Wc, const float* __restrict__ W9,
    const float* __restrict__ W6, const float* __restrict__ W10,
    const float* __restrict__ W7, const float* __restrict__ W12,
    const float* __restrict__ W3, const float* __restrict__ W4,
    const float* __restrict__ bc, const float* __restrict__ b9,
    const float* __restrict__ b6, const float* __restrict__ b10,
    const float* __restrict__ b7, const float* __restrict__ b12,
    const float* __restrict__ b3, const float* __restrict__ b4,
    const float* __restrict__ hp0, const float* __restrict__ hp1,
    const float* __restrict__ W1, const int* __restrict__ data,
    f16* __restrict__ G, float* __restrict__ biasF, f16* __restrict__ W1F,
    f16* __restrict__ W3F, f16* __restrict__ W4F, float* __restrict__ uc,
    int* __restrict__ needed, int* __restrict__ nneed)
{
    const int blk = blockIdx.x;
    const int tid = threadIdx.x;
    if (blk < 5) {
        __shared__ f16 Wt[128 * 136];
        const float* Wsrc; int co;
        switch (blk) {
            case 0: Wsrc = W9;  co = 0;   break;
            case 1: Wsrc = W6;  co = 0;   break;
            case 2: Wsrc = W10; co = 128; break;
            case 3: Wsrc = W7;  co = 128; break;
            default: Wsrc = W12; co = 256; break;
        }
#pragma unroll 4
        for (int i = 0; i < 64; ++i) {
            const int flat = i * 256 + tid;
            const int k = flat >> 7, t = flat & 127;
            Wt[t * 136 + k] = (f16)Wsrc[flat];
        }
        __syncthreads();
        const int w = tid >> 6, lane = tid & 63;
        const int quad = lane >> 4, l16 = lane & 15;
        f32x4 acc[2][8];
#pragma unroll
        for (int dt = 0; dt < 2; ++dt)
#pragma unroll
            for (int nt = 0; nt < 8; ++nt) acc[dt][nt] = (f32x4)(0.0f);
#pragma unroll
        for (int ks = 0; ks < 4; ++ks) {
            const int k0 = ks * 32 + quad * 8;
#pragma unroll
            for (int dt = 0; dt < 2; ++dt) {
                const int row = w * 32 + dt * 16 + l16;
                f16x8 a = cvtf8(Wc + row * 384 + co + k0);
#pragma unroll
                for (int nt = 0; nt < 8; ++nt) {
                    f16x8 b = *(const f16x8*)&Wt[(nt * 16 + l16) * 136 + k0];
                    acc[dt][nt] = __builtin_amdgcn_mfma_f32_16x16x32_f16(a, b, acc[dt][nt], 0, 0, 0);
                }
            }
        }
#pragma unroll
        for (int dt = 0; dt < 2; ++dt)
#pragma unroll
            for (int nt = 0; nt < 8; ++nt)
#pragma unroll
                for (int r = 0; r < 4; ++r)
                    G[(blk * 128 + w * 32 + dt * 16 + quad * 4 + r) * 128 + nt * 16 + l16] =
                        (f16)acc[dt][nt][r];
    } else if (blk == 5) {
        __shared__ float hpl[256];
        __shared__ float bsum[384];
        hpl[tid] = (tid < 128) ? hp0[tid] : hp1[tid - 128];
        for (int i = tid; i < 384; i += 256) {
            float v;
            if (i < 128) v = b9[i] + b6[i];
            else if (i < 256) v = b10[i - 128] + b7[i - 128];
            else v = b12[i - 256];
            bsum[i] = v;
        }
        __syncthreads();
        {   // u = W^T hp
            const int t = tid & 127;
            const float* W = (tid < 128) ? W3 : W4;
            const float* hh = (tid < 128) ? hpl : hpl + 128;
            float s = 0.f;
#pragma unroll 8
            for (int k = 0; k < 128; ++k) s += W[k * 128 + t] * hh[k];
            uc[(tid < 128 ? 0 : 132) + t] = s;
        }
        if (tid == 0) {
            float s = 0.f;
#pragma unroll 8
            for (int k = 0; k < 128; ++k) s += b3[k] * hpl[k];
            uc[128] = s;
        }
        if (tid == 64) {
            float s = 0.f;
#pragma unroll 8
            for (int k = 0; k < 128; ++k) s += b4[k] * hpl[128 + k];
            uc[132 + 128] = s;
        }
        if (tid < 128) {
            float s = bc[tid];
#pragma unroll 8
            for (int k = 0; k < 384; ++k) s += Wc[tid * 384 + k] * bsum[k];
            biasF[tid] = s;
        }
    } else if (blk < 11) {
        const long base = (long)(blk - 6) * 2048;
#pragma unroll
        for (int i = 0; i < 8; ++i) {
            const long c = base + i * 256 + tid;
            *(f16x8*)(W1F + c * 8) = cvtf8(W1 + c * 8);
        }
    } else if (blk == 11) {
#pragma unroll
        for (int i = 0; i < 8; ++i) {
            const long c = i * 256 + tid;
            *(f16x8*)(W3F + c * 8) = cvtf8(W3 + c * 8);
        }
    } else if (blk == 12) {
#pragma unroll
        for (int i = 0; i < 8; ++i) {
            const long c = i * 256 + tid;
            *(f16x8*)(W4F + c * 8) = cvtf8(W4 + c * 8);
        }
    } else {
        // flags + dense id in a single pass: first-touch claims the author
        const int i = (blk - 13) * 256 + tid;     // 32 blocks * 256 = 8192 exact
        const int a = data[i];
        const int old = atomicCAS(&needed[a], 0, -1);
        if (old == 0) needed[a] = 1 + atomicAdd(nneed, 1);
    }
}

// ---------------- K2: scan edges, emit {col, iv} into dense-author buckets ----
__global__ __launch_bounds__(256) void k_count_emit(
    const int* __restrict__ ei0, const float* __restrict__ iv0,
    const int* __restrict__ ei1, const float* __restrict__ iv1,
    const int* __restrict__ needed,
    int* __restrict__ count, int2* __restrict__ bucket)
{
    const int z = blockIdx.z;
    const int* rows = z ? ei1 : ei0;
    const int* cols = rows + N_EDGES;
    const float* ivp = z ? iv1 : iv0;

    const int e0 = (blockIdx.x * 256 + threadIdx.x) * 4;
    if (e0 >= N_EDGES) return;                    // 800000 % 4 == 0
    const int4 rr = *(const int4*)(rows + e0);
    const int ra[4] = {rr.x, rr.y, rr.z, rr.w};
#pragma unroll
    for (int j = 0; j < 4; ++j) {
        const int a = ra[j] - META;
        if ((unsigned)a < (unsigned)AUTHORS) {
            const int id = needed[a];
            if (id) {
                const int d = (z << 13) + id - 1;
                const int slot = atomicAdd(&count[d], 1);
                if (slot < CAP) {
                    int2 rec;
                    rec.x = cols[e0 + j];
                    rec.y = __float_as_int(ivp[e0 + j]);
                    bucket[(long)d * CAP + slot] = rec;
                }
            }
        }
    }
}

// ---------------- K3: hawkes accumulate + agg GEMM fused ----------------------
// 1024 blocks x 512 thr. Each half-wave owns one author: s = sum d_j*sem[col_j],
// t = sum d_j  ->  LDS (16 authors/block). Then 8 waves do the 16x128 @ 128x128
// MFMA (relu(s@W.T + t*b)) and write aggF f16 directly. sbuf round-trip gone.
__global__ __launch_bounds__(512) void k_accum_agg(
    const int* __restrict__ count, const int2* __restrict__ bucket,
    const float* __restrict__ sem0, const float* __restrict__ sem1,
    const float* __restrict__ uc,
    const f16* __restrict__ W3F, const f16* __restrict__ W4F,
    const float* __restrict__ b3, const float* __restrict__ b4,
    f16* __restrict__ aggF)
{
    __shared__ __align__(16) float sld[16][132];   // +4 pad: 2-way banks only
    __shared__ float tl[16];
    const int w = threadIdx.x >> 6, lane = threadIdx.x & 63;
    const int half = lane >> 5, l32 = lane & 31;
    const int gbase = blockIdx.x * 16;             // [0, 16384)
    const int gid = gbase + w * 2 + half;          // one author per half-wave
    const int z = gbase >> 13;
    const float* sem = z ? sem1 : sem0;
    const float* u = uc + (z ? 132 : 0);
    const float cc = u[128];
    const float4 uA = *(const float4*)(u + l32 * 4);

    int n = count[gid];
    n = n < CAP ? n : CAP;
    const long bb = (long)gid * CAP;
    int c1 = 0, c2 = 0; float v1 = 0.f, v2 = 0.f;
    if (l32 < n)      { int2 rec = bucket[bb + l32];      c1 = rec.x; v1 = __int_as_float(rec.y); }
    if (l32 + 32 < n) { int2 rec = bucket[bb + 32 + l32]; c2 = rec.x; v2 = __int_as_float(rec.y); }
    const int nmax = max(n, __shfl_xor(n, 32));    // uniform across wave

    f32x4 s4 = (f32x4)(0.0f);
    float tt = 0.f;
    for (int e = 0; e < nmax; ++e) {
        const int sl = half * 32 + (e & 31);
        const int ce = __shfl(e < 32 ? c1 : c2, sl);     // e uniform
        const float ve = __shfl(e < 32 ? v1 : v2, sl);
        const float4 r = *(const float4*)(sem + (long)ce * DIM + l32 * 4);
        float p = r.x * uA.x + r.y * uA.y + r.z * uA.z + r.w * uA.w;
        p += __shfl_xor(p, 1);  p += __shfl_xor(p, 2);  p += __shfl_xor(p, 4);
        p += __shfl_xor(p, 8);  p += __shfl_xor(p, 16);
        float d = expf(fminf(ve * (p + cc), 60.f));
        d = (e < n) ? d : 0.f;
        s4[0] += d * r.x; s4[1] += d * r.y; s4[2] += d * r.z; s4[3] += d * r.w;
        tt += d;
    }
    const int lrow = w * 2 + half;
    *(f32x4*)&sld[lrow][l32 * 4] = s4;
    if (l32 == 0) tl[lrow] = tt;
    __syncthreads();

    // agg GEMM: 16 rows x 128 cols, each wave one 16-col tile
    const int quad = lane >> 4, l16 = lane & 15;
    const f16* WF = z ? W4F : W3F;
    const float* bia = z ? b4 : b3;
    const int cb = w * 16;
    f32x4 acc = (f32x4)(0.0f);
#pragma unroll
    for (int ks = 0; ks < 4; ++ks) {
        const int k0 = ks * 32 + quad * 8;
        f16x8 a = cvtf8(&sld[l16][k0]);
        f16x8 b = *(const f16x8*)(WF + (cb + l16) * DIM + k0);
        acc = __builtin_amdgcn_mfma_f32_16x16x32_f16(a, b, acc, 0, 0, 0);
    }
    const float bcol = bia[cb + l16];
#pragma unroll
    for (int r = 0; r < 4; ++r) {
        const int row = quad * 4 + r;
        const float v = acc[r] + tl[row] * bcol;
        aggF[(long)(gbase + row) * DIM + cb + l16] = (f16)fmaxf(v, 0.f);
    }
}

// ---------------- K4: head + tail fused ---------------------------------------
// 256 blocks x 512 thr. Block pb computes embcat rows {pb*16..+15} (pre) and
// {pb*16+4096..+15} (suf) into LDS (8 wave-tiles of 16x32), then runs the tail
// out = relu(|pre-suf| @ W1.T + b1) @ W2.T + b2 straight from LDS.
__global__ __launch_bounds__(512) void k_head_tail(
    const float* __restrict__ cne0, const float* __restrict__ cne1,
    const float* __restrict__ str, const int* __restrict__ data,
    const int* __restrict__ needed, const f16* __restrict__ aggF,
    const f16* __restrict__ G, const float* __restrict__ biasF,
    const f16* __restrict__ W1F, const float* __restrict__ b1,
    const float* __restrict__ W2, const float* __restrict__ b2,
    float* __restrict__ out)
{
    __shared__ __align__(16) float emb[32][132];   // rows 0-15 pre, 16-31 suf
    __shared__ float red[8][16][2];
    const int w = threadIdx.x >> 6, lane = threadIdx.x & 63;
    const int quad = lane >> 4, l16 = lane & 15;
    const int pb = blockIdx.x;

    {   // ---- phase A: embcat -> LDS ----
        const int rhalf = w >> 2;                  // 0: pre, 1: suf
        const int cb = (w & 3) * 32;
        const int row = pb * 16 + rhalf * 4096 + l16;
        const int idx = needed[data[row]] - 1;
        f32x4 acc[2];
        acc[0] = (f32x4)(0.0f); acc[1] = (f32x4)(0.0f);
#pragma unroll
        for (int ks = 0; ks < 20; ++ks) {
            const int src = ks >> 2;
            const int k0 = (ks & 3) * 32 + quad * 8;
            f16x8 a;
            if (src == 0 || src == 2 || src == 4) {
                const float* S = (src == 0) ? cne0 : ((src == 2) ? cne1 : str);
                a = cvtf8(S + (long)row * DIM + k0);
            } else {
                a = *(const f16x8*)(aggF + ((src == 1) ? 0L : (8192L * DIM)) + (long)idx * DIM + k0);
            }
            const f16* Gs = G + (long)src * 128 * 128;
#pragma unroll
            for (int nt = 0; nt < 2; ++nt) {
                f16x8 b = *(const f16x8*)(Gs + (cb + nt * 16 + l16) * 128 + k0);
                acc[nt] = __builtin_amdgcn_mfma_f32_16x16x32_f16(a, b, acc[nt], 0, 0, 0);
            }
        }
#pragma unroll
        for (int nt = 0; nt < 2; ++nt) {
            const int col = cb + nt * 16 + l16;
            const float bvv = biasF[col];
#pragma unroll
            for (int r = 0; r < 4; ++r)
                emb[rhalf * 16 + quad * 4 + r][col] = fmaxf(acc[nt][r] + bvv, 0.f);
        }
    }
    __syncthreads();

    // ---- phase B: tail from LDS ----
    const int cbase = w * 80;                      // 8 waves x 80 = 640 cols
    f32x4 acc[5];
#pragma unroll
    for (int t = 0; t < 5; ++t) acc[t] = (f32x4)(0.0f);
#pragma unroll
    for (int ks = 0; ks < 4; ++ks) {
        const int k0 = ks * 32 + quad * 8;
        float4 x1 = *(const float4*)&emb[l16][k0];
        float4 x2 = *(const float4*)&emb[l16][k0 + 4];
        float4 y1 = *(const float4*)&emb[16 + l16][k0];
        float4 y2 = *(const float4*)&emb[16 + l16][k0 + 4];
        f16x8 a;
        a[0] = (f16)fabsf(x1.x - y1.x); a[1] = (f16)fabsf(x1.y - y1.y);
        a[2] = (f16)fabsf(x1.z - y1.z); a[3] = (f16)fabsf(x1.w - y1.w);
        a[4] = (f16)fabsf(x2.x - y2.x); a[5] = (f16)fabsf(x2.y - y2.y);
        a[6] = (f16)fabsf(x2.z - y2.z); a[7] = (f16)fabsf(x2.w - y2.w);
#pragma unroll
        for (int nt = 0; nt < 5; ++nt) {
            f16x8 b = *(const f16x8*)(W1F + (cbase + nt * 16 + l16) * 128 + k0);
            acc[nt] = __builtin_amdgcn_mfma_f32_16x16x32_f16(a, b, acc[nt], 0, 0, 0);
        }
    }
    float p0r[4] = {0.f, 0.f, 0.f, 0.f}, p1r[4] = {0.f, 0.f, 0.f, 0.f};
#pragma unroll
    for (int nt = 0; nt < 5; ++nt) {
        const int col = cbase + nt * 16 + l16;
        const float w20 = W2[col], w21 = W2[640 + col];
        const float bb = b1[col];
#pragma unroll
        for (int r = 0; r < 4; ++r) {
            const float v = fmaxf(acc[nt][r] + bb, 0.f);
            p0r[r] += v * w20;
            p1r[r] += v * w21;
        }
    }
#pragma unroll
    for (int r = 0; r < 4; ++r) {
#pragma unroll
        for (int m = 1; m <= 8; m <<= 1) {
            p0r[r] += __shfl_xor(p0r[r], m);
            p1r[r] += __shfl_xor(p1r[r], m);
        }
    }
    if (l16 == 0) {
#pragma unroll
        for (int r = 0; r < 4; ++r) {
            red[w][quad * 4 + r][0] = p0r[r];
            red[w][quad * 4 + r][1] = p1r[r];
        }
    }
    __syncthreads();
    if (threadIdx.x < 32) {
        const int rr = threadIdx.x >> 1, o = threadIdx.x & 1;
        float s = b2[o];
#pragma unroll
        for (int q = 0; q < 8; ++q) s += red[q][rr][o];
        out[(pb * 16 + rr) * 2 + o] = s;
    }
}

extern "C" void kernel_launch(void* const* d_in, const int* in_sizes, int n_in,
                              void* d_out, int out_size, void* d_ws, size_t ws_size,
                              hipStream_t stream) {
    const float* sem0 = (const float*)d_in[0];
    const float* iv0  = (const float*)d_in[1];
    const int*   ei0  = (const int*)d_in[2];
    const float* sem1 = (const float*)d_in[3];
    const float* iv1  = (const float*)d_in[4];
    const int*   ei1  = (const int*)d_in[5];
    const float* cne0 = (const float*)d_in[6];
    const float* cne1 = (const float*)d_in[7];
    const int*   data = (const int*)d_in[8];
    const float* str  = (const float*)d_in[9];
    const float* W1  = (const float*)d_in[10]; const float* b1  = (const float*)d_in[11];
    const float* W2  = (const float*)d_in[12]; const float* b2  = (const float*)d_in[13];
    const float* W3  = (const float*)d_in[14]; const float* b3  = (const float*)d_in[15];
    const float* W4  = (const float*)d_in[16]; const float* b4  = (const float*)d_in[17];
    const float* W6  = (const float*)d_in[18]; const float* b6  = (const float*)d_in[19];
    const float* W7  = (const float*)d_in[20]; const float* b7  = (const float*)d_in[21];
    const float* W9  = (const float*)d_in[22]; const float* b9  = (const float*)d_in[23];
    const float* W10 = (const float*)d_in[24]; const float* b10 = (const float*)d_in[25];
    const float* W12 = (const float*)d_in[26]; const float* b12 = (const float*)d_in[27];
    const float* Wc  = (const float*)d_in[28]; const float* bc  = (const float*)d_in[29];
    const float* hp0 = (const float*)d_in[30]; const float* hp1 = (const float*)d_in[31];

    char* ws = (char*)d_ws;
    int*    needed = (int*)(ws + 0);            //   200,000
    int*    nneed  = (int*)(ws + 200192);       //         4
    int*    count  = (int*)(ws + 200448);       //    65,536  -> memset end 265,984
    float*  uc     = (float*)(ws + 266240);     //     1,280
    f16*    W3F    = (f16*)(ws + 267520);       //    32,768
    f16*    W4F    = (f16*)(ws + 300288);       //    32,768
    int2*   bucket = (int2*)(ws + 333056);      // 5,242,880
    f16*    aggF   = (f16*)(ws + 14030080);     // 4,194,304
    f16*    G      = (f16*)(ws + 18224384);     //   163,840
    float*  biasF  = (float*)(ws + 18388224);   //       512
    f16*    W1F    = (f16*)(ws + 18388736);     //   163,840

    (void)in_sizes; (void)n_in; (void)out_size; (void)ws_size;

    hipMemsetAsync(ws, 0, 265984, stream);      // needed, nneed, count
    k_prep_fuse<<<45, 256, 0, stream>>>(Wc, W9, W6, W10, W7, W12, W3, W4,
                                        bc, b9, b6, b10, b7, b12, b3, b4,
                                        hp0, hp1, W1, data,
                                        G, biasF, W1F, W3F, W4F, uc,
                                        needed, nneed);
    k_count_emit<<<dim3(782, 1, 2), 256, 0, stream>>>(ei0, iv0, ei1, iv1,
                                                      needed, count, bucket);
    k_accum_agg<<<1024, 512, 0, stream>>>(count, bucket, sem0, sem1, uc,
                                          W3F, W4F, b3, b4, aggF);
    k_head_tail<<<256, 512, 0, stream>>>(cne0, cne1, str, data, needed, aggF,
                                         G, biasF, W1F, b1, W2, b2,
                                         (float*)d_out);
}

// Round 3
// 248.466 us; speedup vs baseline: 1.0959x; 1.0469x over previous
//
#include <hip/hip_runtime.h>
#include <hip/hip_bf16.h>
#include <hip/hip_fp16.h>

typedef _Float16 f16;
typedef __attribute__((ext_vector_type(8))) _Float16 f16x8;
typedef __attribute__((ext_vector_type(4))) float f32x4;

#define N_NODES 100000
#define N_EDGES 800000
#define META 20000
#define AUTHORS 50000
#define BATCH 8192
#define DIM 128
#define CAP 40   // Poisson(~8) edges per (graph,author); P(>40) ~ 1e-16

__device__ __forceinline__ f16x8 cvtf8(const float* p) {
    float4 x = *(const float4*)p, y = *(const float4*)(p + 4);
    f16x8 a;
    a[0] = (f16)x.x; a[1] = (f16)x.y; a[2] = (f16)x.z; a[3] = (f16)x.w;
    a[4] = (f16)y.x; a[5] = (f16)y.y; a[6] = (f16)y.z; a[7] = (f16)y.w;
    return a;
}

// ---------------- K1: dense-id assignment only (tiny, on critical path) -------
__global__ __launch_bounds__(256) void k_ids(
    const int* __restrict__ data, int* __restrict__ needed, int* __restrict__ nneed)
{
    const int i = blockIdx.x * 256 + threadIdx.x;   // 32*256 = 8192 exact
    const int a = data[i];
    const int old = atomicCAS(&needed[a], 0, -1);
    if (old == 0) needed[a] = 1 + atomicAdd(nneed, 1);
}

// ---------------- K2: edge scan + ALL weight prep in one dispatch -------------
// blk 0-4 : G_f = Wc[:,co:co+128] @ Wsrc  (MFMA, LDS-transposed B)  -> f16
// blk 5   : biasF, uc (u0,c0,u1,c1)
// blk 6-10: W1F = f16(W1)
// blk 11  : W3F ; blk 12 : W4F
// blk 13+ : scan edges, emit {col, iv} into dense-author buckets
__global__ __launch_bounds__(256) void k_emit_prep(
    const float* __restrict__ Wc, const float* __restrict__ W9,
    const float* __restrict__ W6, const float* __restrict__ W10,
    const float* __restrict__ W7, const float* __restrict__ W12,
    const float* __restrict__ W3, const float* __restrict__ W4,
    const float* __restrict__ bc, const float* __restrict__ b9,
    const float* __restrict__ b6, const float* __restrict__ b10,
    const float* __restrict__ b7, const float* __restrict__ b12,
    const float* __restrict__ b3, const float* __restrict__ b4,
    const float* __restrict__ hp0, const float* __restrict__ hp1,
    const float* __restrict__ W1,
    const int* __restrict__ ei0, const float* __restrict__ iv0,
    const int* __restrict__ ei1, const float* __restrict__ iv1,
    const int* __restrict__ needed,
    f16* __restrict__ G, float* __restrict__ biasF, f16* __restrict__ W1F,
    f16* __restrict__ W3F, f16* __restrict__ W4F, float* __restrict__ uc,
    int* __restrict__ count, int2* __restrict__ bucket)
{
    const int blk = blockIdx.x;
    const int tid = threadIdx.x;
    if (blk < 5) {
        __shared__ f16 Wt[128 * 136];
        const float* Wsrc; int co;
        switch (blk) {
            case 0: Wsrc = W9;  co = 0;   break;
            case 1: Wsrc = W6;  co = 0;   break;
            case 2: Wsrc = W10; co = 128; break;
            case 3: Wsrc = W7;  co = 128; break;
            default: Wsrc = W12; co = 256; break;
        }
#pragma unroll 4
        for (int i = 0; i < 64; ++i) {
            const int flat = i * 256 + tid;
            const int k = flat >> 7, t = flat & 127;
            Wt[t * 136 + k] = (f16)Wsrc[flat];
        }
        __syncthreads();
        const int w = tid >> 6, lane = tid & 63;
        const int quad = lane >> 4, l16 = lane & 15;
        f32x4 acc[2][8];
#pragma unroll
        for (int dt = 0; dt < 2; ++dt)
#pragma unroll
            for (int nt = 0; nt < 8; ++nt) acc[dt][nt] = (f32x4)(0.0f);
#pragma unroll
        for (int ks = 0; ks < 4; ++ks) {
            const int k0 = ks * 32 + quad * 8;
#pragma unroll
            for (int dt = 0; dt < 2; ++dt) {
                const int row = w * 32 + dt * 16 + l16;
                f16x8 a = cvtf8(Wc + row * 384 + co + k0);
#pragma unroll
                for (int nt = 0; nt < 8; ++nt) {
                    f16x8 b = *(const f16x8*)&Wt[(nt * 16 + l16) * 136 + k0];
                    acc[dt][nt] = __builtin_amdgcn_mfma_f32_16x16x32_f16(a, b, acc[dt][nt], 0, 0, 0);
                }
            }
        }
#pragma unroll
        for (int dt = 0; dt < 2; ++dt)
#pragma unroll
            for (int nt = 0; nt < 8; ++nt)
#pragma unroll
                for (int r = 0; r < 4; ++r)
                    G[(blk * 128 + w * 32 + dt * 16 + quad * 4 + r) * 128 + nt * 16 + l16] =
                        (f16)acc[dt][nt][r];
    } else if (blk == 5) {
        __shared__ float hpl[256];
        __shared__ float bsum[384];
        hpl[tid] = (tid < 128) ? hp0[tid] : hp1[tid - 128];
        for (int i = tid; i < 384; i += 256) {
            float v;
            if (i < 128) v = b9[i] + b6[i];
            else if (i < 256) v = b10[i - 128] + b7[i - 128];
            else v = b12[i - 256];
            bsum[i] = v;
        }
        __syncthreads();
        {   // u = W^T hp
            const int t = tid & 127;
            const float* W = (tid < 128) ? W3 : W4;
            const float* hh = (tid < 128) ? hpl : hpl + 128;
            float s = 0.f;
#pragma unroll 8
            for (int k = 0; k < 128; ++k) s += W[k * 128 + t] * hh[k];
            uc[(tid < 128 ? 0 : 132) + t] = s;
        }
        if (tid == 0) {
            float s = 0.f;
#pragma unroll 8
            for (int k = 0; k < 128; ++k) s += b3[k] * hpl[k];
            uc[128] = s;
        }
        if (tid == 64) {
            float s = 0.f;
#pragma unroll 8
            for (int k = 0; k < 128; ++k) s += b4[k] * hpl[128 + k];
            uc[132 + 128] = s;
        }
        if (tid < 128) {
            float s = bc[tid];
#pragma unroll 8
            for (int k = 0; k < 384; ++k) s += Wc[tid * 384 + k] * bsum[k];
            biasF[tid] = s;
        }
    } else if (blk < 11) {
        const long base = (long)(blk - 6) * 2048;
#pragma unroll
        for (int i = 0; i < 8; ++i) {
            const long c = base + i * 256 + tid;
            *(f16x8*)(W1F + c * 8) = cvtf8(W1 + c * 8);
        }
    } else if (blk == 11) {
#pragma unroll
        for (int i = 0; i < 8; ++i) {
            const long c = i * 256 + tid;
            *(f16x8*)(W3F + c * 8) = cvtf8(W3 + c * 8);
        }
    } else if (blk == 12) {
#pragma unroll
        for (int i = 0; i < 8; ++i) {
            const long c = i * 256 + tid;
            *(f16x8*)(W4F + c * 8) = cvtf8(W4 + c * 8);
        }
    } else {
        // ---- edge scan: 782 blocks per graph, 4 edges/thread -----------------
        const int b = blk - 13;
        const int z = b / 782;
        const int xb = b - z * 782;
        const int e0 = (xb * 256 + tid) * 4;
        if (e0 >= N_EDGES) return;
        const int* rows = z ? ei1 : ei0;
        const int* cols = rows + N_EDGES;
        const float* ivp = z ? iv1 : iv0;
        const int4 rr = *(const int4*)(rows + e0);
        const int4 cc4 = *(const int4*)(cols + e0);
        const float4 vv4 = *(const float4*)(ivp + e0);
        const int ra[4] = {rr.x, rr.y, rr.z, rr.w};
        const int ca[4] = {cc4.x, cc4.y, cc4.z, cc4.w};
        const float va[4] = {vv4.x, vv4.y, vv4.z, vv4.w};
#pragma unroll
        for (int j = 0; j < 4; ++j) {
            const int a = ra[j] - META;
            if ((unsigned)a < (unsigned)AUTHORS) {
                const int id = needed[a];
                if (id) {
                    const int d = (z << 13) + id - 1;
                    const int slot = atomicAdd(&count[d], 1);
                    if (slot < CAP) {
                        int2 rec;
                        rec.x = ca[j];
                        rec.y = __float_as_int(va[j]);
                        bucket[(long)d * CAP + slot] = rec;
                    }
                }
            }
        }
    }
}

// ---------------- K3: hawkes accumulate + agg GEMM fused ----------------------
// 1024 blocks x 512 thr. Each half-wave owns one author: s = sum d_j*sem[col_j],
// t = sum d_j  ->  LDS (16 authors/block). Then 8 waves do the 16x128 @ 128x128
// MFMA (relu(s@W.T + t*b)) and write aggF f16 directly.
__global__ __launch_bounds__(512) void k_accum_agg(
    const int* __restrict__ count, const int2* __restrict__ bucket,
    const float* __restrict__ sem0, const float* __restrict__ sem1,
    const float* __restrict__ uc,
    const f16* __restrict__ W3F, const f16* __restrict__ W4F,
    const float* __restrict__ b3, const float* __restrict__ b4,
    f16* __restrict__ aggF)
{
    __shared__ __align__(16) float sld[16][132];   // +4 pad: 2-way banks only
    __shared__ float tl[16];
    const int w = threadIdx.x >> 6, lane = threadIdx.x & 63;
    const int half = lane >> 5, l32 = lane & 31;
    const int gbase = blockIdx.x * 16;             // [0, 16384)
    const int gid = gbase + w * 2 + half;          // one author per half-wave
    const int z = gbase >> 13;
    const float* sem = z ? sem1 : sem0;
    const float* u = uc + (z ? 132 : 0);
    const float cc = u[128];
    const float4 uA = *(const float4*)(u + l32 * 4);

    int n = count[gid];
    n = n < CAP ? n : CAP;
    const long bb = (long)gid * CAP;
    int c1 = 0, c2 = 0; float v1 = 0.f, v2 = 0.f;
    if (l32 < n)      { int2 rec = bucket[bb + l32];      c1 = rec.x; v1 = __int_as_float(rec.y); }
    if (l32 + 32 < n) { int2 rec = bucket[bb + 32 + l32]; c2 = rec.x; v2 = __int_as_float(rec.y); }
    const int nmax = max(n, __shfl_xor(n, 32));    // uniform across wave

    f32x4 s4 = (f32x4)(0.0f);
    float tt = 0.f;
    // 2-way unrolled: two independent gather+reduce chains per iteration
    for (int e = 0; e < nmax; e += 2) {
        const int f = e + 1;
        const int ce0 = __shfl(e < 32 ? c1 : c2, half * 32 + (e & 31));
        const float ve0 = __shfl(e < 32 ? v1 : v2, half * 32 + (e & 31));
        const int ce1 = __shfl(f < 32 ? c1 : c2, half * 32 + (f & 31));
        const float ve1 = __shfl(f < 32 ? v1 : v2, half * 32 + (f & 31));
        const float4 r0 = *(const float4*)(sem + (long)ce0 * DIM + l32 * 4);
        const float4 r1 = *(const float4*)(sem + (long)ce1 * DIM + l32 * 4);
        float p0 = r0.x * uA.x + r0.y * uA.y + r0.z * uA.z + r0.w * uA.w;
        float p1 = r1.x * uA.x + r1.y * uA.y + r1.z * uA.z + r1.w * uA.w;
        p0 += __shfl_xor(p0, 1);  p1 += __shfl_xor(p1, 1);
        p0 += __shfl_xor(p0, 2);  p1 += __shfl_xor(p1, 2);
        p0 += __shfl_xor(p0, 4);  p1 += __shfl_xor(p1, 4);
        p0 += __shfl_xor(p0, 8);  p1 += __shfl_xor(p1, 8);
        p0 += __shfl_xor(p0, 16); p1 += __shfl_xor(p1, 16);
        // exp(min(x,60)) == exp2(min(x*log2e, 86.562))
        float d0 = exp2f(fminf(ve0 * (p0 + cc) * 1.44269504089f, 86.562f));
        float d1 = exp2f(fminf(ve1 * (p1 + cc) * 1.44269504089f, 86.562f));
        d0 = (e < n) ? d0 : 0.f;
        d1 = (f < n) ? d1 : 0.f;
        s4[0] += d0 * r0.x + d1 * r1.x;
        s4[1] += d0 * r0.y + d1 * r1.y;
        s4[2] += d0 * r0.z + d1 * r1.z;
        s4[3] += d0 * r0.w + d1 * r1.w;
        tt += d0 + d1;
    }
    const int lrow = w * 2 + half;
    *(f32x4*)&sld[lrow][l32 * 4] = s4;
    if (l32 == 0) tl[lrow] = tt;
    __syncthreads();

    // agg GEMM: 16 rows x 128 cols, each wave one 16-col tile
    const int quad = lane >> 4, l16 = lane & 15;
    const f16* WF = z ? W4F : W3F;
    const float* bia = z ? b4 : b3;
    const int cb = w * 16;
    f32x4 acc = (f32x4)(0.0f);
#pragma unroll
    for (int ks = 0; ks < 4; ++ks) {
        const int k0 = ks * 32 + quad * 8;
        f16x8 a = cvtf8(&sld[l16][k0]);
        f16x8 b = *(const f16x8*)(WF + (cb + l16) * DIM + k0);
        acc = __builtin_amdgcn_mfma_f32_16x16x32_f16(a, b, acc, 0, 0, 0);
    }
    const float bcol = bia[cb + l16];
#pragma unroll
    for (int r = 0; r < 4; ++r) {
        const int row = quad * 4 + r;
        const float v = acc[r] + tl[row] * bcol;
        aggF[(long)(gbase + row) * DIM + cb + l16] = (f16)fmaxf(v, 0.f);
    }
}

// ---------------- K4: head + tail fused ---------------------------------------
__global__ __launch_bounds__(512) void k_head_tail(
    const float* __restrict__ cne0, const float* __restrict__ cne1,
    const float* __restrict__ str, const int* __restrict__ data,
    const int* __restrict__ needed, const f16* __restrict__ aggF,
    const f16* __restrict__ G, const float* __restrict__ biasF,
    const f16* __restrict__ W1F, const float* __restrict__ b1,
    const float* __restrict__ W2, const float* __restrict__ b2,
    float* __restrict__ out)
{
    __shared__ __align__(16) float emb[32][132];   // rows 0-15 pre, 16-31 suf
    __shared__ float red[8][16][2];
    const int w = threadIdx.x >> 6, lane = threadIdx.x & 63;
    const int quad = lane >> 4, l16 = lane & 15;
    const int pb = blockIdx.x;

    {   // ---- phase A: embcat -> LDS ----
        const int rhalf = w >> 2;                  // 0: pre, 1: suf
        const int cb = (w & 3) * 32;
        const int row = pb * 16 + rhalf * 4096 + l16;
        const int idx = needed[data[row]] - 1;
        f32x4 acc[2];
        acc[0] = (f32x4)(0.0f); acc[1] = (f32x4)(0.0f);
#pragma unroll
        for (int ks = 0; ks < 20; ++ks) {
            const int src = ks >> 2;
            const int k0 = (ks & 3) * 32 + quad * 8;
            f16x8 a;
            if (src == 0 || src == 2 || src == 4) {
                const float* S = (src == 0) ? cne0 : ((src == 2) ? cne1 : str);
                a = cvtf8(S + (long)row * DIM + k0);
            } else {
                a = *(const f16x8*)(aggF + ((src == 1) ? 0L : (8192L * DIM)) + (long)idx * DIM + k0);
            }
            const f16* Gs = G + (long)src * 128 * 128;
#pragma unroll
            for (int nt = 0; nt < 2; ++nt) {
                f16x8 b = *(const f16x8*)(Gs + (cb + nt * 16 + l16) * 128 + k0);
                acc[nt] = __builtin_amdgcn_mfma_f32_16x16x32_f16(a, b, acc[nt], 0, 0, 0);
            }
        }
#pragma unroll
        for (int nt = 0; nt < 2; ++nt) {
            const int col = cb + nt * 16 + l16;
            const float bvv = biasF[col];
#pragma unroll
            for (int r = 0; r < 4; ++r)
                emb[rhalf * 16 + quad * 4 + r][col] = fmaxf(acc[nt][r] + bvv, 0.f);
        }
    }
    __syncthreads();

    // ---- phase B: tail from LDS ----
    const int cbase = w * 80;                      // 8 waves x 80 = 640 cols
    f32x4 acc[5];
#pragma unroll
    for (int t = 0; t < 5; ++t) acc[t] = (f32x4)(0.0f);
#pragma unroll
    for (int ks = 0; ks < 4; ++ks) {
        const int k0 = ks * 32 + quad * 8;
        float4 x1 = *(const float4*)&emb[l16][k0];
        float4 x2 = *(const float4*)&emb[l16][k0 + 4];
        float4 y1 = *(const float4*)&emb[16 + l16][k0];
        float4 y2 = *(const float4*)&emb[16 + l16][k0 + 4];
        f16x8 a;
        a[0] = (f16)fabsf(x1.x - y1.x); a[1] = (f16)fabsf(x1.y - y1.y);
        a[2] = (f16)fabsf(x1.z - y1.z); a[3] = (f16)fabsf(x1.w - y1.w);
        a[4] = (f16)fabsf(x2.x - y2.x); a[5] = (f16)fabsf(x2.y - y2.y);
        a[6] = (f16)fabsf(x2.z - y2.z); a[7] = (f16)fabsf(x2.w - y2.w);
#pragma unroll
        for (int nt = 0; nt < 5; ++nt) {
            f16x8 b = *(const f16x8*)(W1F + (cbase + nt * 16 + l16) * 128 + k0);
            acc[nt] = __builtin_amdgcn_mfma_f32_16x16x32_f16(a, b, acc[nt], 0, 0, 0);
        }
    }
    float p0r[4] = {0.f, 0.f, 0.f, 0.f}, p1r[4] = {0.f, 0.f, 0.f, 0.f};
#pragma unroll
    for (int nt = 0; nt < 5; ++nt) {
        const int col = cbase + nt * 16 + l16;
        const float w20 = W2[col], w21 = W2[640 + col];
        const float bb = b1[col];
#pragma unroll
        for (int r = 0; r < 4; ++r) {
            const float v = fmaxf(acc[nt][r] + bb, 0.f);
            p0r[r] += v * w20;
            p1r[r] += v * w21;
        }
    }
#pragma unroll
    for (int r = 0; r < 4; ++r) {
#pragma unroll
        for (int m = 1; m <= 8; m <<= 1) {
            p0r[r] += __shfl_xor(p0r[r], m);
            p1r[r] += __shfl_xor(p1r[r], m);
        }
    }
    if (l16 == 0) {
#pragma unroll
        for (int r = 0; r < 4; ++r) {
            red[w][quad * 4 + r][0] = p0r[r];
            red[w][quad * 4 + r][1] = p1r[r];
        }
    }
    __syncthreads();
    if (threadIdx.x < 32) {
        const int rr = threadIdx.x >> 1, o = threadIdx.x & 1;
        float s = b2[o];
#pragma unroll
        for (int q = 0; q < 8; ++q) s += red[q][rr][o];
        out[(pb * 16 + rr) * 2 + o] = s;
    }
}

extern "C" void kernel_launch(void* const* d_in, const int* in_sizes, int n_in,
                              void* d_out, int out_size, void* d_ws, size_t ws_size,
                              hipStream_t stream) {
    const float* sem0 = (const float*)d_in[0];
    const float* iv0  = (const float*)d_in[1];
    const int*   ei0  = (const int*)d_in[2];
    const float* sem1 = (const float*)d_in[3];
    const float* iv1  = (const float*)d_in[4];
    const int*   ei1  = (const int*)d_in[5];
    const float* cne0 = (const float*)d_in[6];
    const float* cne1 = (const float*)d_in[7];
    const int*   data = (const int*)d_in[8];
    const float* str  = (const float*)d_in[9];
    const float* W1  = (const float*)d_in[10]; const float* b1  = (const float*)d_in[11];
    const float* W2  = (const float*)d_in[12]; const float* b2  = (const float*)d_in[13];
    const float* W3  = (const float*)d_in[14]; const float* b3  = (const float*)d_in[15];
    const float* W4  = (const float*)d_in[16]; const float* b4  = (const float*)d_in[17];
    const float* W6  = (const float*)d_in[18]; const float* b6  = (const float*)d_in[19];
    const float* W7  = (const float*)d_in[20]; const float* b7  = (const float*)d_in[21];
    const float* W9  = (const float*)d_in[22]; const float* b9  = (const float*)d_in[23];
    const float* W10 = (const float*)d_in[24]; const float* b10 = (const float*)d_in[25];
    const float* W12 = (const float*)d_in[26]; const float* b12 = (const float*)d_in[27];
    const float* Wc  = (const float*)d_in[28]; const float* bc  = (const float*)d_in[29];
    const float* hp0 = (const float*)d_in[30]; const float* hp1 = (const float*)d_in[31];

    char* ws = (char*)d_ws;
    int*    needed = (int*)(ws + 0);            //   200,000
    int*    nneed  = (int*)(ws + 200192);       //         4
    int*    count  = (int*)(ws + 200448);       //    65,536  -> memset end 265,984
    float*  uc     = (float*)(ws + 266240);     //     1,280
    f16*    W3F    = (f16*)(ws + 267520);       //    32,768
    f16*    W4F    = (f16*)(ws + 300288);       //    32,768
    int2*   bucket = (int2*)(ws + 333056);      // 5,242,880
    f16*    aggF   = (f16*)(ws + 14030080);     // 4,194,304
    f16*    G      = (f16*)(ws + 18224384);     //   163,840
    float*  biasF  = (float*)(ws + 18388224);   //       512
    f16*    W1F    = (f16*)(ws + 18388736);     //   163,840

    (void)in_sizes; (void)n_in; (void)out_size; (void)ws_size;

    hipMemsetAsync(ws, 0, 265984, stream);      // needed, nneed, count
    k_ids<<<32, 256, 0, stream>>>(data, needed, nneed);
    k_emit_prep<<<13 + 782 * 2, 256, 0, stream>>>(Wc, W9, W6, W10, W7, W12, W3, W4,
                                                  bc, b9, b6, b10, b7, b12, b3, b4,
                                                  hp0, hp1, W1,
                                                  ei0, iv0, ei1, iv1, needed,
                                                  G, biasF, W1F, W3F, W4F, uc,
                                                  count, bucket);
    k_accum_agg<<<1024, 512, 0, stream>>>(count, bucket, sem0, sem1, uc,
                                          W3F, W4F, b3, b4, aggF);
    k_head_tail<<<256, 512, 0, stream>>>(cne0, cne1, str, data, needed, aggF,
                                         G, biasF, W1F, b1, W2, b2,
                                         (float*)d_out);
}